// Round 9
// baseline (25.565 us; speedup 1.0000x reference)
//
#include <hip/hip_runtime.h>

#define B_TOT 16384
#define F_DIM 512
#define T_DIM 256
#define N_DIM 256
#define NBLK  1024          // stage1 blocks; 4096 waves x 4 rows = 16384 rows

__device__ __forceinline__ float wave_sum(float v) {
#pragma unroll
    for (int o = 32; o; o >>= 1) v += __shfl_xor(v, o, 64);
    return v;
}
__device__ __forceinline__ float wave_prod(float v) {
#pragma unroll
    for (int o = 32; o; o >>= 1) v *= __shfl_xor(v, o, 64);
    return v;
}
// logp of the chosen logit: chosen - lse(chosen,other) == -log(1+exp(other-chosen))
__device__ __forceinline__ float pick_lp(float chosen, float other) {
    return -__logf(1.f + __expf(other - chosen));
}

// Per-row reduction math (row data already in registers / LDS slice).
__device__ __forceinline__ void do_row(
    const float4& g0, const float4& g1, const float4& g2, const float4& g3,
    const float4& pv, const float4& tg, const float* __restrict__ pvlds,
    unsigned long long lt,
    float& acc_pick, float& acc_dsq, float& acc_multi, int& acc_tc)
{
    float p = 0.f;
    p += pick_lp(g0.y, g0.x);
    p += pick_lp(g0.w, g0.z);
    p += pick_lp(g1.y, g1.x);
    p += pick_lp(g1.w, g1.z);
    p += pick_lp(g2.x, g2.y);   // f >= 256: chosen = component 0
    p += pick_lp(g2.z, g2.w);
    p += pick_lp(g3.x, g3.y);
    p += pick_lp(g3.z, g3.w);
    acc_pick += p;

    bool m0 = g0.y > g0.x;      // t = 4l
    bool m1 = g0.w > g0.z;      // t = 4l+1
    bool m2 = g1.y > g1.x;      // t = 4l+2
    bool m3 = g1.w > g1.z;      // t = 4l+3
    unsigned long long q0 = __ballot(m0);
    unsigned long long q1 = __ballot(m1);
    unsigned long long q2 = __ballot(m2);
    unsigned long long q3 = __ballot(m3);

    int e0 = __popcll(q0 & lt) + __popcll(q1 & lt)
           + __popcll(q2 & lt) + __popcll(q3 & lt);
    int e1 = e0 + (m0 ? 1 : 0);
    int e2 = e1 + (m1 ? 1 : 0);
    int e3 = e2 + (m2 ? 1 : 0);
    acc_tc += __popcll(q0) + __popcll(q1) + __popcll(q2) + __popcll(q3);

    float dsq = 0.f, d;
    if (m0) { d = pvlds[e0] - tg.x; dsq += d * d; }
    if (m1) { d = pvlds[e1] - tg.y; dsq += d * d; }
    if (m2) { d = pvlds[e2] - tg.z; dsq += d * d; }
    if (m3) { d = pvlds[e3] - tg.w; dsq += d * d; }
    acc_dsq += dsq;

    float prod = wave_prod(pv.x * pv.y * pv.z * pv.w);
    float pm1 = prod - 1.f;
    acc_multi += pm1 * pm1;
}

// One wave handles 4 rows. ALL 24 float4 loads issue before any compute;
// in-order vmcnt waits mean row k's compute overlaps rows k+1..3's loads
// (free software pipeline). No __syncthreads until the final block combine.
__global__ __launch_bounds__(256) void setcrit_stage1(
    const float* __restrict__ pred_class,
    const float* __restrict__ pred_v,
    const float* __restrict__ targets,
    float* __restrict__ partial)
{
    __shared__ float s_predv[4][4][N_DIM];   // [row k][wave][n]
    __shared__ float s_fin[4][4];

    const int tid = threadIdx.x;
    const int l   = tid & 63;
    const int w   = tid >> 6;
    const unsigned long long lt = (1ull << l) - 1ull;
    const int wave_id = blockIdx.x * 4 + w;   // 4096 waves, 4 rows each

    float4 g0[4], g1[4], g2[4], g3[4], pv[4], tg[4];

    // ---- issue all 24 loads back-to-back (coalesced, independent) ----
#pragma unroll
    for (int k = 0; k < 4; ++k) {
        const int b = wave_id + k * (NBLK * 4);
        const float* lgp = pred_class + (size_t)b * (2 * F_DIM);
        g0[k] = *(const float4*)(lgp + 8 * l);           // f = 4l, 4l+1
        g1[k] = *(const float4*)(lgp + 8 * l + 4);       // f = 4l+2, 4l+3
        g2[k] = *(const float4*)(lgp + 512 + 8 * l);     // f = 256+4l, 257+4l
        g3[k] = *(const float4*)(lgp + 512 + 8 * l + 4); // f = 258+4l, 259+4l
        pv[k] = *(const float4*)(pred_v  + (size_t)b * N_DIM + 4 * l);
        tg[k] = *(const float4*)(targets + (size_t)b * T_DIM + 4 * l);
    }

    // ---- stage pred_v rows (wave-private slices; no barrier needed) ----
#pragma unroll
    for (int k = 0; k < 4; ++k)
        *(float4*)(&s_predv[k][w][4 * l]) = pv[k];

    float acc_pick = 0.f, acc_dsq = 0.f, acc_multi = 0.f;
    int   acc_tc = 0;

#pragma unroll
    for (int k = 0; k < 4; ++k)
        do_row(g0[k], g1[k], g2[k], g3[k], pv[k], tg[k], s_predv[k][w],
               lt, acc_pick, acc_dsq, acc_multi, acc_tc);

    float pickS = wave_sum(acc_pick);
    float dsqS  = wave_sum(acc_dsq);
    if (l == 0) {
        s_fin[w][0] = pickS;
        s_fin[w][1] = acc_multi;
        s_fin[w][2] = dsqS;
        s_fin[w][3] = (float)acc_tc;
    }
    __syncthreads();
    if (tid == 0) {
        float v0 = 0.f, v1 = 0.f, v2 = 0.f, v3 = 0.f;
#pragma unroll
        for (int k = 0; k < 4; ++k) {
            v0 += s_fin[k][0]; v1 += s_fin[k][1];
            v2 += s_fin[k][2]; v3 += s_fin[k][3];
        }
        partial[0 * NBLK + blockIdx.x] = v0;
        partial[1 * NBLK + blockIdx.x] = v1;
        partial[2 * NBLK + blockIdx.x] = v2 * (1.f / (float)T_DIM);
        partial[3 * NBLK + blockIdx.x] = v3 * (1.f / (float)T_DIM);
    }
}

// Wave w reduces component w via 4 independent float4 loads/lane, one
// shuffle tree, one barrier.
__global__ __launch_bounds__(256) void setcrit_stage2(
    const float* __restrict__ partial, float* __restrict__ out)
{
    __shared__ float s_red[4];
    const int tid = threadIdx.x;
    const int l   = tid & 63;
    const int w   = tid >> 6;

    const float4* p4 = (const float4*)(partial + w * NBLK);
    float4 v4 = make_float4(0.f, 0.f, 0.f, 0.f);
#pragma unroll
    for (int i = 0; i < NBLK / 256; ++i) {
        float4 t = p4[i * 64 + l];
        v4.x += t.x; v4.y += t.y; v4.z += t.z; v4.w += t.w;
    }
    float v = wave_sum((v4.x + v4.y) + (v4.z + v4.w));
    if (l == 0) s_red[w] = v;
    __syncthreads();

    if (tid == 0) {
        float loss_label = -s_red[0] / ((float)B_TOT * (float)F_DIM);
        float loss_multi = s_red[1] / (float)B_TOT;
        float loss_true  = s_red[2] / (float)B_TOT;
        float f1         = s_red[3] / (float)B_TOT;
        float r = loss_multi + loss_true;
        out[0] = loss_label + r;
        out[1] = loss_label;
        out[2] = r;
        out[3] = loss_multi;
        out[4] = loss_true;
        out[5] = f1;
    }
}

extern "C" void kernel_launch(void* const* d_in, const int* in_sizes, int n_in,
                              void* d_out, int out_size, void* d_ws, size_t ws_size,
                              hipStream_t stream) {
    const float* pred_class = (const float*)d_in[0];
    const float* pred_v     = (const float*)d_in[1];
    const float* targets    = (const float*)d_in[2];
    float* partial = (float*)d_ws;  // 4 * NBLK floats = 16 KB

    setcrit_stage1<<<NBLK, 256, 0, stream>>>(pred_class, pred_v, targets, partial);
    setcrit_stage2<<<1, 256, 0, stream>>>(partial, (float*)d_out);
}

// Round 10
// 23.491 us; speedup vs baseline: 1.0883x; 1.0883x over previous
//
#include <hip/hip_runtime.h>

#define B_TOT 16384
#define F_DIM 512
#define T_DIM 256
#define N_DIM 256
#define NBLK  2048

__device__ __forceinline__ float wave_sum(float v) {
#pragma unroll
    for (int o = 32; o; o >>= 1) v += __shfl_xor(v, o, 64);
    return v;
}
__device__ __forceinline__ float wave_prod(float v) {
#pragma unroll
    for (int o = 32; o; o >>= 1) v *= __shfl_xor(v, o, 64);
    return v;
}
// logp of the chosen logit: chosen - lse(chosen,other) == -log(1+exp(other-chosen))
__device__ __forceinline__ float pick_lp(float chosen, float other) {
    return -__logf(1.f + __expf(other - chosen));
}

// Round-3 structure, DENSE lane mapping: every load has 16B (or 8B) lane
// stride, so each instruction's payload is a contiguous block (16 cachelines
// per logits load instead of 32 half-used ones). Lane l owns f-pairs
// {2l,2l+1}, {128+2l,129+2l} (mask+target range) and {256+2l,...},{384+2l,...}.
__global__ __launch_bounds__(256, 4) void setcrit_stage1(
    const float* __restrict__ pred_class,
    const float* __restrict__ pred_v,
    const float* __restrict__ targets,
    float* __restrict__ partial)
{
    __shared__ float s_predv[4][N_DIM];   // private slice per wave
    __shared__ float s_fin[4][4];

    const int tid = threadIdx.x;
    const int l   = tid & 63;
    const int w   = tid >> 6;
    const unsigned long long lt = (1ull << l) - 1ull;
    const int wave_id = blockIdx.x * 4 + w;   // 8192 waves, 2 rows each

    float acc_pick = 0.f, acc_dsq = 0.f, acc_multi = 0.f;
    int   acc_tc = 0;

#pragma unroll
    for (int i = 0; i < 2; ++i) {
        const int b = i * (NBLK * 4) + wave_id;
        const float* lgp = pred_class + (size_t)b * (2 * F_DIM);
        const float* pvp = pred_v     + (size_t)b * N_DIM;
        const float* tgp = targets    + (size_t)b * T_DIM;

        // ---- dense coalesced row loads (16B/8B lane stride) ----
        float4 g0 = *(const float4*)(lgp + 4 * l);          // f = 2l, 2l+1
        float4 g1 = *(const float4*)(lgp + 256 + 4 * l);    // f = 128+2l, 129+2l
        float4 g2 = *(const float4*)(lgp + 512 + 4 * l);    // f = 256+2l, 257+2l
        float4 g3 = *(const float4*)(lgp + 768 + 4 * l);    // f = 384+2l, 385+2l
        float4 pv = *(const float4*)(pvp + 4 * l);          // n = 4l..4l+3
        float2 t0 = *(const float2*)(tgp + 2 * l);          // t = 2l, 2l+1
        float2 t1 = *(const float2*)(tgp + 128 + 2 * l);    // t = 128+2l, 129+2l

        *(float4*)(&s_predv[w][4 * l]) = pv;                // stage for gather

        // ---- log-softmax picks: f<256 -> logp[1], f>=256 -> logp[0] ----
        float p = 0.f;
        p += pick_lp(g0.y, g0.x);
        p += pick_lp(g0.w, g0.z);
        p += pick_lp(g1.y, g1.x);
        p += pick_lp(g1.w, g1.z);
        p += pick_lp(g2.x, g2.y);
        p += pick_lp(g2.z, g2.w);
        p += pick_lp(g3.x, g3.y);
        p += pick_lp(g3.z, g3.w);
        acc_pick += p;

        // ---- mask + exclusive prefix: t=2l,2l+1 in [0,128), 128+2l,129+2l ----
        bool m0 = g0.y > g0.x;   // t = 2l
        bool m1 = g0.w > g0.z;   // t = 2l+1
        bool m2 = g1.y > g1.x;   // t = 128+2l
        bool m3 = g1.w > g1.z;   // t = 129+2l
        unsigned long long b0 = __ballot(m0);
        unsigned long long b1 = __ballot(m1);
        unsigned long long b2 = __ballot(m2);
        unsigned long long b3 = __ballot(m3);

        int e0 = __popcll(b0 & lt) + __popcll(b1 & lt);
        int e1 = e0 + (m0 ? 1 : 0);
        int h  = __popcll(b0) + __popcll(b1);      // total masked in [0,128)
        int e2 = h + __popcll(b2 & lt) + __popcll(b3 & lt);
        int e3 = e2 + (m2 ? 1 : 0);
        acc_tc += h + __popcll(b2) + __popcll(b3);

        // ---- matched gather + squared error (tc==0 rows contribute 0) ----
        float dsq = 0.f, d;
        if (m0) { d = s_predv[w][e0] - t0.x; dsq += d * d; }
        if (m1) { d = s_predv[w][e1] - t0.y; dsq += d * d; }
        if (m2) { d = s_predv[w][e2] - t1.x; dsq += d * d; }
        if (m3) { d = s_predv[w][e3] - t1.y; dsq += d * d; }
        acc_dsq += dsq;

        // ---- product over the row ----
        float prod = wave_prod(pv.x * pv.y * pv.z * pv.w);
        float pm1 = prod - 1.f;
        acc_multi += pm1 * pm1;
    }

    float pickS = wave_sum(acc_pick);
    float dsqS  = wave_sum(acc_dsq);
    if (l == 0) {
        s_fin[w][0] = pickS;
        s_fin[w][1] = acc_multi;
        s_fin[w][2] = dsqS;
        s_fin[w][3] = (float)acc_tc;
    }
    __syncthreads();
    if (tid == 0) {
        float v0 = 0.f, v1 = 0.f, v2 = 0.f, v3 = 0.f;
#pragma unroll
        for (int k = 0; k < 4; ++k) {
            v0 += s_fin[k][0]; v1 += s_fin[k][1];
            v2 += s_fin[k][2]; v3 += s_fin[k][3];
        }
        partial[0 * NBLK + blockIdx.x] = v0;
        partial[1 * NBLK + blockIdx.x] = v1;
        partial[2 * NBLK + blockIdx.x] = v2 * (1.f / (float)T_DIM);
        partial[3 * NBLK + blockIdx.x] = v3 * (1.f / (float)T_DIM);
    }
}

// Wave w reduces component w: 32 independent loads/lane, one shuffle tree,
// one barrier, thread 0 composes the 6 outputs.
__global__ __launch_bounds__(256) void setcrit_stage2(
    const float* __restrict__ partial, float* __restrict__ out)
{
    __shared__ float s_red[4];
    const int tid = threadIdx.x;
    const int l   = tid & 63;
    const int w   = tid >> 6;

    float v = 0.f;
#pragma unroll
    for (int i = 0; i < NBLK / 64; ++i)
        v += partial[w * NBLK + i * 64 + l];
    v = wave_sum(v);
    if (l == 0) s_red[w] = v;
    __syncthreads();

    if (tid == 0) {
        float loss_label = -s_red[0] / ((float)B_TOT * (float)F_DIM);
        float loss_multi = s_red[1] / (float)B_TOT;
        float loss_true  = s_red[2] / (float)B_TOT;
        float f1         = s_red[3] / (float)B_TOT;
        float r = loss_multi + loss_true;
        out[0] = loss_label + r;
        out[1] = loss_label;
        out[2] = r;
        out[3] = loss_multi;
        out[4] = loss_true;
        out[5] = f1;
    }
}

extern "C" void kernel_launch(void* const* d_in, const int* in_sizes, int n_in,
                              void* d_out, int out_size, void* d_ws, size_t ws_size,
                              hipStream_t stream) {
    const float* pred_class = (const float*)d_in[0];
    const float* pred_v     = (const float*)d_in[1];
    const float* targets    = (const float*)d_in[2];
    float* partial = (float*)d_ws;  // 4 * NBLK floats = 32 KB

    setcrit_stage1<<<NBLK, 256, 0, stream>>>(pred_class, pred_v, targets, partial);
    setcrit_stage2<<<1, 256, 0, stream>>>(partial, (float*)d_out);
}